// Round 4
// baseline (293.872 us; speedup 1.0000x reference)
//
#include <hip/hip_runtime.h>
#include <cstdint>
#include <cstddef>

// Problem constants (B=32, D=256, H=32, W=32, K=1024), N = B*H*W = 32768.
// z_e layout: [b][d][h][w]; point n=(b,hw).
//
// MFMA path: fp32 -> 3x bf16 split (z = z0+z1+z2 exact to ~2^-26 rel).
// dot(z,c) = sum of 6 concat-K segments: (z0,c0),(z1,c0),(z2,c0),(z0,c1),(z1,c1),(z0,c2)
// -> bf16 GEMM M=32768 N=1024 K=1536, error ~ fp32 accumulation (numpy-grade).

typedef __attribute__((ext_vector_type(8))) short bf16x8;
typedef __attribute__((ext_vector_type(4))) float f32x4;

#define GL2LDS(g, l) __builtin_amdgcn_global_load_lds( \
    (__attribute__((address_space(1))) const void*)(g), \
    (__attribute__((address_space(3))) void*)(l), 16, 0, 0)

__device__ __forceinline__ unsigned short rne_bf16(float f) {
    unsigned u = __float_as_uint(f);
    return (unsigned short)((u + 0x7FFFu + ((u >> 16) & 1u)) >> 16);
}
__device__ __forceinline__ float bf16_to_f(unsigned short h) {
    return __uint_as_float((unsigned)h << 16);
}

// ---------------------------------------------------------------------------
// codebook row norms ||c_k||^2 (fp32, from original codebook)
// ---------------------------------------------------------------------------
__global__ __launch_bounds__(256)
void vq_cnorm_kernel(const float* __restrict__ cb, float* __restrict__ cnorm)
{
    const int k = blockIdx.x * 256 + threadIdx.x;  // grid=4
    const float4* row = reinterpret_cast<const float4*>(cb + (size_t)k * 256);
    float s0 = 0.f, s1 = 0.f, s2 = 0.f, s3 = 0.f;
#pragma unroll 8
    for (int i = 0; i < 64; ++i) {
        float4 v = row[i];
        s0 = fmaf(v.x, v.x, s0);
        s1 = fmaf(v.y, v.y, s1);
        s2 = fmaf(v.z, v.z, s2);
        s3 = fmaf(v.w, v.w, s3);
    }
    cnorm[k] = (s0 + s1) + (s2 + s3);
}

// ---------------------------------------------------------------------------
// codebook split: [1024][256] fp32 -> c0,c1,c2 bf16 (same layout, K-contig)
// ---------------------------------------------------------------------------
__global__ __launch_bounds__(256)
void vq_csplit_kernel(const float* __restrict__ cb, unsigned short* __restrict__ c0,
                      unsigned short* __restrict__ c1, unsigned short* __restrict__ c2)
{
    const int idx = blockIdx.x * 256 + threadIdx.x;   // grid 256 -> 65536 threads x4
    float4 v = reinterpret_cast<const float4*>(cb)[idx];
    float f[4] = { v.x, v.y, v.z, v.w };
    ushort4 h0, h1, h2;
    unsigned short* p0[4] = { &h0.x, &h0.y, &h0.z, &h0.w };
    unsigned short* p1[4] = { &h1.x, &h1.y, &h1.z, &h1.w };
    unsigned short* p2[4] = { &h2.x, &h2.y, &h2.z, &h2.w };
#pragma unroll
    for (int j = 0; j < 4; ++j) {
        unsigned short b0 = rne_bf16(f[j]); float r1 = f[j] - bf16_to_f(b0);
        unsigned short b1 = rne_bf16(r1);   float r2 = r1 - bf16_to_f(b1);
        unsigned short b2 = rne_bf16(r2);
        *p0[j] = b0; *p1[j] = b1; *p2[j] = b2;
    }
    reinterpret_cast<ushort4*>(c0)[idx] = h0;
    reinterpret_cast<ushort4*>(c1)[idx] = h1;
    reinterpret_cast<ushort4*>(c2)[idx] = h2;
}

// ---------------------------------------------------------------------------
// z split+transpose: z[b][d][hw] fp32 -> z0,z1,z2 bf16 [n][d] (K-contiguous)
// Block: 256 thr, 64 hw x 256 d. LDS transpose (pad 264 keeps 16B-aligned reads).
// ---------------------------------------------------------------------------
__global__ __launch_bounds__(256)
void vq_zsplit_kernel(const float* __restrict__ z, unsigned short* __restrict__ z0,
                      unsigned short* __restrict__ z1, unsigned short* __restrict__ z2)
{
    __shared__ float zl[64 * 264];
    const int t = threadIdx.x, blk = blockIdx.x;        // 512 blocks
    const int b = blk >> 4, hw0 = (blk & 15) << 6;
    const float* zb = z + ((size_t)b << 18) + hw0;
#pragma unroll 8
    for (int i = 0; i < 64; ++i) {
        int idx = i * 256 + t;
        int d = idx >> 6, hwl = idx & 63;               // coalesced global read
        zl[hwl * 264 + d] = zb[(size_t)d * 1024 + hwl];
    }
    __syncthreads();
    const int n0 = (b << 10) + hw0;
#pragma unroll
    for (int p = 0; p < 8; ++p) {
        const int hwl = p * 8 + (t >> 5);
        const int d0 = (t & 31) * 8;
        const float* src = &zl[hwl * 264 + d0];
        unsigned short h0[8], h1[8], h2[8];
#pragma unroll
        for (int j = 0; j < 8; ++j) {
            float f = src[j];
            unsigned short b0 = rne_bf16(f);  float r1 = f - bf16_to_f(b0);
            unsigned short b1 = rne_bf16(r1); float r2 = r1 - bf16_to_f(b1);
            unsigned short b2 = rne_bf16(r2);
            h0[j] = b0; h1[j] = b1; h2[j] = b2;
        }
        const size_t o = (size_t)(n0 + hwl) * 256 + d0;  // coalesced 16B/lane writes
        ushort4 a;
        a = ushort4{h0[0],h0[1],h0[2],h0[3]}; *reinterpret_cast<ushort4*>(z0 + o)     = a;
        a = ushort4{h0[4],h0[5],h0[6],h0[7]}; *reinterpret_cast<ushort4*>(z0 + o + 4) = a;
        a = ushort4{h1[0],h1[1],h1[2],h1[3]}; *reinterpret_cast<ushort4*>(z1 + o)     = a;
        a = ushort4{h1[4],h1[5],h1[6],h1[7]}; *reinterpret_cast<ushort4*>(z1 + o + 4) = a;
        a = ushort4{h2[0],h2[1],h2[2],h2[3]}; *reinterpret_cast<ushort4*>(z2 + o)     = a;
        a = ushort4{h2[4],h2[5],h2[6],h2[7]}; *reinterpret_cast<ushort4*>(z2 + o + 4) = a;
    }
}

// ---------------------------------------------------------------------------
// MFMA GEMM + fused argmin. m97-style: 128x128 tile, BK=64, 4 waves (2x2),
// 16x16x32 bf16 MFMA, global_load_lds w=16, 2 barriers/K-step, K=1536 (6 segs).
// Epilogue: dist = cnorm - 2*acc; ordered-uint pack (u<<32|code); shfl-reduce
// over 16-lane col group; atomicMin u64 per point across 8 column-blocks.
// ---------------------------------------------------------------------------
__global__ __launch_bounds__(256)
void vq_mfma_argmin_kernel(const unsigned short* __restrict__ zp,
                           const unsigned short* __restrict__ cp,
                           const float* __restrict__ cnorm,
                           unsigned long long* __restrict__ packed)
{
    __shared__ unsigned short At[128 * 64];
    __shared__ unsigned short Bt[128 * 64];

    const int t = threadIdx.x, l = t & 63, w = t >> 6;
    const int wr = w >> 1, wc = w & 1;
    const int bm = blockIdx.x >> 3, bn = blockIdx.x & 7;   // bn fast: same-bm blocks adjacent
    const int arow = bm * 128, brow = bn * 128;

    const unsigned short* zparts[3] = { zp, zp + 8388608u, zp + 16777216u };
    const unsigned short* cparts[3] = { cp, cp + 262144u,  cp + 524288u };

    f32x4 acc[4][4];
#pragma unroll
    for (int m = 0; m < 4; ++m)
#pragma unroll
        for (int n = 0; n < 4; ++n) acc[m][n] = f32x4{0.f, 0.f, 0.f, 0.f};

    const int srow = w * 8 + (l >> 3);     // staging row within 32-row group
    const int scol = (l & 7) * 8;          // staging col (elements)

    // segment tables: A part, B part per 256-K segment
    const int ASEG[6] = { 0, 1, 2, 0, 1, 0 };
    const int BSEG[6] = { 0, 0, 0, 1, 1, 2 };

#pragma unroll
    for (int seg = 0; seg < 6; ++seg) {
        const unsigned short* As = zparts[ASEG[seg]];
        const unsigned short* Bs = cparts[BSEG[seg]];
#pragma unroll
        for (int k4 = 0; k4 < 4; ++k4) {
            const int ko = k4 * 64;
            __syncthreads();               // previous tile fully consumed
#pragma unroll
            for (int i = 0; i < 4; ++i) {  // 4 issues x 4 waves x 1KB = 16KB per tile
                GL2LDS(As + (size_t)(arow + i * 32 + srow) * 256 + ko + scol,
                       &At[(i * 32 + w * 8) * 64]);
                GL2LDS(Bs + (size_t)(brow + i * 32 + srow) * 256 + ko + scol,
                       &Bt[(i * 32 + w * 8) * 64]);
            }
            __syncthreads();               // drains vmcnt: tiles ready
#pragma unroll
            for (int kk = 0; kk < 2; ++kk) {
                bf16x8 a[4], b[4];
#pragma unroll
                for (int m = 0; m < 4; ++m)
                    a[m] = *reinterpret_cast<const bf16x8*>(
                        &At[(wr * 64 + m * 16 + (l & 15)) * 64 + kk * 32 + (l >> 4) * 8]);
#pragma unroll
                for (int n = 0; n < 4; ++n)
                    b[n] = *reinterpret_cast<const bf16x8*>(
                        &Bt[(wc * 64 + n * 16 + (l & 15)) * 64 + kk * 32 + (l >> 4) * 8]);
#pragma unroll
                for (int m = 0; m < 4; ++m)
#pragma unroll
                    for (int n = 0; n < 4; ++n)
                        acc[m][n] = __builtin_amdgcn_mfma_f32_16x16x32_bf16(
                            a[m], b[n], acc[m][n], 0, 0, 0);
            }
        }
    }

    // epilogue: fused argmin
    int coln[4]; float cnv[4];
#pragma unroll
    for (int n = 0; n < 4; ++n) {
        coln[n] = brow + wc * 64 + n * 16 + (l & 15);
        cnv[n] = cnorm[coln[n]];
    }
#pragma unroll
    for (int m = 0; m < 4; ++m) {
#pragma unroll
        for (int j = 0; j < 4; ++j) {
            unsigned long long best = 0xFFFFFFFFFFFFFFFFull;
#pragma unroll
            for (int n = 0; n < 4; ++n) {
                float d = fmaf(-2.0f, acc[m][n][j], cnv[n]);
                unsigned u = __float_as_uint(d);
                u = (u & 0x80000000u) ? ~u : (u | 0x80000000u);   // order-preserving map
                unsigned long long pk = ((unsigned long long)u << 32) | (unsigned)coln[n];
                best = pk < best ? pk : best;
            }
#pragma unroll
            for (int mask = 1; mask <= 8; mask <<= 1) {
                unsigned long long o = __shfl_xor(best, mask, 64);
                best = o < best ? o : best;
            }
            if ((l & 15) == 0) {
                const int row = arow + wr * 64 + m * 16 + (l >> 4) * 4 + j;
                atomicMin(&packed[row], best);
            }
        }
    }
}

// ---------------------------------------------------------------------------
// gather (packed): z_q write, out_idx write, vq_loss accumulate
// ---------------------------------------------------------------------------
__global__ __launch_bounds__(256, 2)
void vq_gather_packed_kernel(const float* __restrict__ cb, const float* __restrict__ z,
                             const unsigned long long* __restrict__ packed,
                             float* __restrict__ out_zq, float* __restrict__ out_idx,
                             float* __restrict__ loss)
{
    __shared__ float rows[64 * 257];
    __shared__ int   ks[64];
    __shared__ float wsum[4];

    const int t   = threadIdx.x;
    const int blk = blockIdx.x;            // 512 blocks
    const int b   = blk >> 4;
    const int hw0 = (blk & 15) << 6;
    const int n0  = blk << 6;

    if (t < 64) {
        const int k = (int)(packed[n0 + t] & 0xFFFFFFFFull);
        ks[t] = k;
        out_idx[n0 + t] = (float)k;
    }
    __syncthreads();

#pragma unroll 4
    for (int i = 0; i < 64; ++i) {
        rows[i * 257 + t] = cb[(size_t)ks[i] * 256 + t];
    }
    __syncthreads();

    const int dq = t >> 6;
    const int hw = t & 63;
    const size_t obase = ((size_t)b << 18) + hw0 + hw;
    float sum = 0.f;
#pragma unroll 4
    for (int dd = 0; dd < 64; ++dd) {
        const int d = (dq << 6) + dd;
        const float  q  = rows[hw * 257 + d];
        const size_t a  = obase + (size_t)d * 1024;
        const float  zv = z[a];
        out_zq[a] = q;
        const float diff = q - zv;
        sum = fmaf(diff, diff, sum);
    }
#pragma unroll
    for (int m = 1; m <= 32; m <<= 1) sum += __shfl_xor(sum, m, 64);
    if ((t & 63) == 0) wsum[t >> 6] = sum;
    __syncthreads();
    if (t == 0) {
        const float s = (wsum[0] + wsum[1]) + (wsum[2] + wsum[3]);
        atomicAdd(loss, s * (1.25f / 8388608.0f));   // (1+0.25)*SSE/(B*D*H*W)
    }
}

// ===========================================================================
// FALLBACK PATH (ws too small): round-3 fp32 VALU kernels, known-passing.
// ===========================================================================
__global__ __launch_bounds__(256)
void vq_transpose_kernel(const float* __restrict__ cb, float* __restrict__ ctT)
{
    __shared__ float tile[64 * 65];
    const int t  = threadIdx.x;
    const int kb = blockIdx.x >> 2, db = blockIdx.x & 3;
    const int k0 = kb << 6, d0 = db << 6;
#pragma unroll
    for (int i = 0; i < 16; ++i) {
        int idx = i * 256 + t;
        int r = idx >> 6, c = idx & 63;
        tile[r * 65 + c] = cb[(size_t)(k0 + r) * 256 + d0 + c];
    }
    __syncthreads();
#pragma unroll
    for (int i = 0; i < 16; ++i) {
        int idx = i * 256 + t;
        int r = idx >> 6, c = idx & 63;
        ctT[(size_t)(d0 + r) * 1024 + k0 + c] = tile[c * 65 + r];
    }
}

__global__ __launch_bounds__(512, 2)
void vq_argmin_kernel(const float* __restrict__ z, const float* __restrict__ ctT,
                      const float* __restrict__ cnorm, int* __restrict__ codes,
                      float* __restrict__ out_idx)
{
    __shared__ float zt[256 * 64];
    __shared__ float ct[16 * 256];
    const int t = threadIdx.x, tx = t & 63, ty = t >> 6, p0 = ty << 3;
    const int blk = blockIdx.x, b = blk >> 4, hw0 = (blk & 15) << 6;
    const float* zbase = z + ((size_t)b << 18) + hw0;
#pragma unroll
    for (int i = 0; i < 8; ++i) {
        int idx = i * 512 + t;
        int d = idx >> 4, c4 = (idx & 15) << 2;
        float4 v = *reinterpret_cast<const float4*>(zbase + (size_t)d * 1024 + c4);
        *reinterpret_cast<float4*>(&zt[d * 64 + c4]) = v;
    }
    float minv[8]; int mini[8];
#pragma unroll
    for (int i = 0; i < 8; ++i) { minv[i] = 3.0e38f; mini[i] = 0; }
    const float* zrd = &zt[p0];
    const float* crd = &ct[tx << 2];
    for (int kt = 0; kt < 4; ++kt) {
        const int k0 = kt << 8;
        float acc[8][4];
#pragma unroll
        for (int i = 0; i < 8; ++i)
#pragma unroll
            for (int j = 0; j < 4; ++j) acc[i][j] = 0.f;
        for (int dc = 0; dc < 16; ++dc) {
            const int d0 = dc << 4;
            __syncthreads();
#pragma unroll
            for (int i = 0; i < 2; ++i) {
                int idx = i * 512 + t;
                int r = idx >> 6, c4 = (idx & 63) << 2;
                float4 v = *reinterpret_cast<const float4*>(ctT + (size_t)(d0 + r) * 1024 + k0 + c4);
                *reinterpret_cast<float4*>(&ct[r * 256 + c4]) = v;
            }
            __syncthreads();
            const float* zp = zrd + d0 * 64;
#pragma unroll
            for (int d = 0; d < 16; ++d) {
                float4 za = *reinterpret_cast<const float4*>(zp + d * 64);
                float4 zb = *reinterpret_cast<const float4*>(zp + d * 64 + 4);
                float4 cc = *reinterpret_cast<const float4*>(crd + d * 256);
#define VQ_FMA_ROW(ii, zv)                          \
                acc[ii][0] = fmaf(zv, cc.x, acc[ii][0]); \
                acc[ii][1] = fmaf(zv, cc.y, acc[ii][1]); \
                acc[ii][2] = fmaf(zv, cc.z, acc[ii][2]); \
                acc[ii][3] = fmaf(zv, cc.w, acc[ii][3]);
                VQ_FMA_ROW(0, za.x) VQ_FMA_ROW(1, za.y) VQ_FMA_ROW(2, za.z) VQ_FMA_ROW(3, za.w)
                VQ_FMA_ROW(4, zb.x) VQ_FMA_ROW(5, zb.y) VQ_FMA_ROW(6, zb.z) VQ_FMA_ROW(7, zb.w)
#undef VQ_FMA_ROW
            }
        }
#pragma unroll
        for (int j = 0; j < 4; ++j) {
            const int k = k0 + (tx << 2) + j;
            const float cn = cnorm[k];
#pragma unroll
            for (int i = 0; i < 8; ++i) {
                float dist = fmaf(-2.0f, acc[i][j], cn);
                if (dist < minv[i]) { minv[i] = dist; mini[i] = k; }
            }
        }
    }
#pragma unroll
    for (int m = 1; m <= 32; m <<= 1) {
#pragma unroll
        for (int i = 0; i < 8; ++i) {
            float ov = __shfl_xor(minv[i], m, 64);
            int   oi = __shfl_xor(mini[i], m, 64);
            if (ov < minv[i] || (ov == minv[i] && oi < mini[i])) { minv[i] = ov; mini[i] = oi; }
        }
    }
    if (tx == 0) {
        const int n0 = (blk << 6) + p0;
#pragma unroll
        for (int i = 0; i < 8; ++i) {
            codes[n0 + i]   = mini[i];
            out_idx[n0 + i] = (float)mini[i];
        }
    }
}

__global__ __launch_bounds__(256, 2)
void vq_gather_kernel(const float* __restrict__ cb, const float* __restrict__ z,
                      const int* __restrict__ codes, float* __restrict__ out_zq,
                      float* __restrict__ loss)
{
    __shared__ float rows[64 * 257];
    __shared__ int   ks[64];
    __shared__ float wsum[4];
    const int t = threadIdx.x, blk = blockIdx.x;
    const int b = blk >> 4, hw0 = (blk & 15) << 6, n0 = blk << 6;
    if (t < 64) ks[t] = codes[n0 + t];
    __syncthreads();
#pragma unroll 4
    for (int i = 0; i < 64; ++i) rows[i * 257 + t] = cb[(size_t)ks[i] * 256 + t];
    __syncthreads();
    const int dq = t >> 6, hw = t & 63;
    const size_t obase = ((size_t)b << 18) + hw0 + hw;
    float sum = 0.f;
#pragma unroll 4
    for (int dd = 0; dd < 64; ++dd) {
        const int d = (dq << 6) + dd;
        const float  q  = rows[hw * 257 + d];
        const size_t a  = obase + (size_t)d * 1024;
        const float  zv = z[a];
        out_zq[a] = q;
        const float diff = q - zv;
        sum = fmaf(diff, diff, sum);
    }
#pragma unroll
    for (int m = 1; m <= 32; m <<= 1) sum += __shfl_xor(sum, m, 64);
    if ((t & 63) == 0) wsum[t >> 6] = sum;
    __syncthreads();
    if (t == 0) {
        const float s = (wsum[0] + wsum[1]) + (wsum[2] + wsum[3]);
        atomicAdd(loss, s * (1.25f / 8388608.0f));
    }
}

// ---------------------------------------------------------------------------
extern "C" void kernel_launch(void* const* d_in, const int* in_sizes, int n_in,
                              void* d_out, int out_size, void* d_ws, size_t ws_size,
                              hipStream_t stream)
{
    (void)in_sizes; (void)n_in; (void)out_size;

    const float* z  = (const float*)d_in[0];   // 32*256*32*32 fp32
    const float* cb = (const float*)d_in[1];   // 1024*256 fp32

    float* out      = (float*)d_out;
    float* out_zq   = out;                     // 8388608
    float* out_idx  = out + 8388608;           // 32768 (indices as float values)
    float* out_loss = out + 8421376;           // 1

    // MFMA-path workspace: packed(256KB) | z0|z1|z2 (16MB each) | c0|c1|c2 | cnorm
    const size_t NEED = 262144ull + 3ull * 16777216ull + 3ull * 524288ull + 4096ull;

    if (ws_size >= NEED) {
        unsigned long long* packed = (unsigned long long*)d_ws;
        unsigned short* z0 = (unsigned short*)((char*)d_ws + 262144);
        unsigned short* z1 = z0 + 8388608u;
        unsigned short* z2 = z1 + 8388608u;
        unsigned short* c0 = z2 + 8388608u;
        unsigned short* c1 = c0 + 262144u;
        unsigned short* c2 = c1 + 262144u;
        float* cnorm = (float*)(c2 + 262144u);

        hipMemsetAsync(out_loss, 0, sizeof(float), stream);
        hipMemsetAsync(packed, 0xFF, 262144, stream);
        vq_csplit_kernel<<<256, 256, 0, stream>>>(cb, c0, c1, c2);
        vq_cnorm_kernel<<<4, 256, 0, stream>>>(cb, cnorm);
        vq_zsplit_kernel<<<512, 256, 0, stream>>>(z, z0, z1, z2);
        vq_mfma_argmin_kernel<<<2048, 256, 0, stream>>>(z0, c0, cnorm, packed);
        vq_gather_packed_kernel<<<512, 256, 0, stream>>>(cb, z, packed, out_zq, out_idx, out_loss);
    } else {
        // fallback: round-3 fp32 path (ws >= 1.38MB known OK)
        float* ctT   = (float*)d_ws;
        float* cnorm = ctT + 256 * 1024;
        int*   codes = (int*)(cnorm + 1024);

        hipMemsetAsync(out_loss, 0, sizeof(float), stream);
        vq_transpose_kernel<<<64, 256, 0, stream>>>(cb, ctT);
        vq_cnorm_kernel<<<4, 256, 0, stream>>>(cb, cnorm);
        vq_argmin_kernel<<<512, 512, 0, stream>>>(z, ctT, cnorm, codes, out_idx);
        vq_gather_kernel<<<512, 256, 0, stream>>>(cb, z, codes, out_zq, out_loss);
    }
}

// Round 5
// 184.513 us; speedup vs baseline: 1.5927x; 1.5927x over previous
//
#include <hip/hip_runtime.h>
#include <cstdint>
#include <cstddef>

// Problem constants (B=32, D=256, H=32, W=32, K=1024), N = B*H*W = 32768.
// z_e layout: [b][d][h][w]; point n=(b,hw).
//
// MFMA path: fp32 -> 3x bf16 split (z = z0+z1+z2 exact to ~2^-26 rel).
// dot(z,c) = sum of 6 concat-K segments: (z0,c0),(z1,c0),(z2,c0),(z0,c1),(z1,c1),(z0,c2)
// -> bf16 GEMM M=32768 N=1024 K=1536, error ~ fp32 accumulation (numpy-grade).

typedef __attribute__((ext_vector_type(8))) short bf16x8;
typedef __attribute__((ext_vector_type(4))) float f32x4;

#define GL2LDS(g, l) __builtin_amdgcn_global_load_lds( \
    (__attribute__((address_space(1))) const void*)(g), \
    (__attribute__((address_space(3))) void*)(l), 16, 0, 0)

__device__ __forceinline__ unsigned short rne_bf16(float f) {
    unsigned u = __float_as_uint(f);
    return (unsigned short)((u + 0x7FFFu + ((u >> 16) & 1u)) >> 16);
}
__device__ __forceinline__ float bf16_to_f(unsigned short h) {
    return __uint_as_float((unsigned)h << 16);
}

// ---------------------------------------------------------------------------
// codebook row norms ||c_k||^2 (fp32, from original codebook)
// ---------------------------------------------------------------------------
__global__ __launch_bounds__(256)
void vq_cnorm_kernel(const float* __restrict__ cb, float* __restrict__ cnorm)
{
    const int k = blockIdx.x * 256 + threadIdx.x;  // grid=4
    const float4* row = reinterpret_cast<const float4*>(cb + (size_t)k * 256);
    float s0 = 0.f, s1 = 0.f, s2 = 0.f, s3 = 0.f;
#pragma unroll 8
    for (int i = 0; i < 64; ++i) {
        float4 v = row[i];
        s0 = fmaf(v.x, v.x, s0);
        s1 = fmaf(v.y, v.y, s1);
        s2 = fmaf(v.z, v.z, s2);
        s3 = fmaf(v.w, v.w, s3);
    }
    cnorm[k] = (s0 + s1) + (s2 + s3);
}

// ---------------------------------------------------------------------------
// codebook split: [1024][256] fp32 -> c0,c1,c2 bf16 (same layout, K-contig)
// ---------------------------------------------------------------------------
__global__ __launch_bounds__(256)
void vq_csplit_kernel(const float* __restrict__ cb, unsigned short* __restrict__ c0,
                      unsigned short* __restrict__ c1, unsigned short* __restrict__ c2)
{
    const int idx = blockIdx.x * 256 + threadIdx.x;   // grid 256 -> 65536 threads x4
    float4 v = reinterpret_cast<const float4*>(cb)[idx];
    float f[4] = { v.x, v.y, v.z, v.w };
    ushort4 h0, h1, h2;
    unsigned short* p0[4] = { &h0.x, &h0.y, &h0.z, &h0.w };
    unsigned short* p1[4] = { &h1.x, &h1.y, &h1.z, &h1.w };
    unsigned short* p2[4] = { &h2.x, &h2.y, &h2.z, &h2.w };
#pragma unroll
    for (int j = 0; j < 4; ++j) {
        unsigned short b0 = rne_bf16(f[j]); float r1 = f[j] - bf16_to_f(b0);
        unsigned short b1 = rne_bf16(r1);   float r2 = r1 - bf16_to_f(b1);
        unsigned short b2 = rne_bf16(r2);
        *p0[j] = b0; *p1[j] = b1; *p2[j] = b2;
    }
    reinterpret_cast<ushort4*>(c0)[idx] = h0;
    reinterpret_cast<ushort4*>(c1)[idx] = h1;
    reinterpret_cast<ushort4*>(c2)[idx] = h2;
}

// ---------------------------------------------------------------------------
// z split+transpose: z[b][d][hw] fp32 -> z0,z1,z2 bf16 [n][d] (K-contiguous)
// Block: 256 thr, 64 hw x 256 d. LDS transpose (pad 264 keeps 16B-aligned reads).
// ---------------------------------------------------------------------------
__global__ __launch_bounds__(256)
void vq_zsplit_kernel(const float* __restrict__ z, unsigned short* __restrict__ z0,
                      unsigned short* __restrict__ z1, unsigned short* __restrict__ z2)
{
    __shared__ float zl[64 * 264];
    const int t = threadIdx.x, blk = blockIdx.x;        // 512 blocks
    const int b = blk >> 4, hw0 = (blk & 15) << 6;
    const float* zb = z + ((size_t)b << 18) + hw0;
#pragma unroll 8
    for (int i = 0; i < 64; ++i) {
        int idx = i * 256 + t;
        int d = idx >> 6, hwl = idx & 63;               // coalesced global read
        zl[hwl * 264 + d] = zb[(size_t)d * 1024 + hwl];
    }
    __syncthreads();
    const int n0 = (b << 10) + hw0;
#pragma unroll
    for (int p = 0; p < 8; ++p) {
        const int hwl = p * 8 + (t >> 5);
        const int d0 = (t & 31) * 8;
        const float* src = &zl[hwl * 264 + d0];
        unsigned short h0[8], h1[8], h2[8];
#pragma unroll
        for (int j = 0; j < 8; ++j) {
            float f = src[j];
            unsigned short b0 = rne_bf16(f);  float r1 = f - bf16_to_f(b0);
            unsigned short b1 = rne_bf16(r1); float r2 = r1 - bf16_to_f(b1);
            unsigned short b2 = rne_bf16(r2);
            h0[j] = b0; h1[j] = b1; h2[j] = b2;
        }
        const size_t o = (size_t)(n0 + hwl) * 256 + d0;  // coalesced 16B/lane writes
        ushort4 a;
        a = ushort4{h0[0],h0[1],h0[2],h0[3]}; *reinterpret_cast<ushort4*>(z0 + o)     = a;
        a = ushort4{h0[4],h0[5],h0[6],h0[7]}; *reinterpret_cast<ushort4*>(z0 + o + 4) = a;
        a = ushort4{h1[0],h1[1],h1[2],h1[3]}; *reinterpret_cast<ushort4*>(z1 + o)     = a;
        a = ushort4{h1[4],h1[5],h1[6],h1[7]}; *reinterpret_cast<ushort4*>(z1 + o + 4) = a;
        a = ushort4{h2[0],h2[1],h2[2],h2[3]}; *reinterpret_cast<ushort4*>(z2 + o)     = a;
        a = ushort4{h2[4],h2[5],h2[6],h2[7]}; *reinterpret_cast<ushort4*>(z2 + o + 4) = a;
    }
}

// ---------------------------------------------------------------------------
// MFMA GEMM + fused argmin. 128x128 tile, BK=64, 4 waves (2x2), 16x16x32 bf16,
// global_load_lds w=16, 2 barriers/K-step, K=1536 (6 segments).
//
// T2 LDS swizzle (both-sides, rule #21): tile rows are 64 bf16 = 128B; the
// 16B chunk at (row, c) is stored at chunk c ^ (row&7). gload_lds writes LDS
// linearly, so the GLOBAL source chunk per lane is pre-swizzled
// (scol = ((l&7) ^ ((l>>3)&7))*8) and the ds_read applies the same XOR
// (fragment rows have row&7 == l&7). 16-way bank conflict -> conflict-free.
//
// T1 XCD swizzle (bijective, 2048%8==0): nid=(bid&7)*256+(bid>>3); bm=nid>>3,
// bn=nid&7 -> each XCD owns a contiguous 32-bm chunk, bn-fast, so each
// A-panel is fetched once per XCD-L2 and reused by 8 consecutive blocks.
//
// Epilogue: dist = cnorm - 2*acc; ordered-uint pack (u<<32|code); shfl-reduce
// over 16-lane col group; atomicMin u64 per point across 8 column-blocks.
// ---------------------------------------------------------------------------
__global__ __launch_bounds__(256)
void vq_mfma_argmin_kernel(const unsigned short* __restrict__ zp,
                           const unsigned short* __restrict__ cp,
                           const float* __restrict__ cnorm,
                           unsigned long long* __restrict__ packed)
{
    __shared__ unsigned short At[128 * 64];
    __shared__ unsigned short Bt[128 * 64];

    const int t = threadIdx.x, l = t & 63, w = t >> 6;
    const int wr = w >> 1, wc = w & 1;
    const int nid = ((blockIdx.x & 7) << 8) | (blockIdx.x >> 3);   // XCD swizzle
    const int bm = nid >> 3, bn = nid & 7;
    const int arow = bm * 128, brow = bn * 128;

    const unsigned short* zparts[3] = { zp, zp + 8388608u, zp + 16777216u };
    const unsigned short* cparts[3] = { cp, cp + 262144u,  cp + 524288u };

    f32x4 acc[4][4];
#pragma unroll
    for (int m = 0; m < 4; ++m)
#pragma unroll
        for (int n = 0; n < 4; ++n) acc[m][n] = f32x4{0.f, 0.f, 0.f, 0.f};

    // staging: lane l covers row (l>>3), chunk (l&7); pre-swizzle global chunk
    const int srow = w * 8 + (l >> 3);
    const int scol = (((l & 7) ^ ((l >> 3) & 7))) * 8;

    // fragment-read swizzled chunk offsets (row&7 == l&7 for fragment rows)
    const int lo16 = l & 15, hi4 = l >> 4, l7 = l & 7;
    const int coff0 = ((hi4    ) ^ l7) * 8;   // kk=0: chunk = 0*4 + hi4
    const int coff1 = ((hi4 + 4) ^ l7) * 8;   // kk=1: chunk = 1*4 + hi4
    const unsigned short* Arow = &At[(wr * 64 + lo16) * 64];
    const unsigned short* Brow = &Bt[(wc * 64 + lo16) * 64];

    // segment tables: A part, B part per 256-K segment
    const int ASEG[6] = { 0, 1, 2, 0, 1, 0 };
    const int BSEG[6] = { 0, 0, 0, 1, 1, 2 };

#pragma unroll
    for (int seg = 0; seg < 6; ++seg) {
        const unsigned short* As = zparts[ASEG[seg]];
        const unsigned short* Bs = cparts[BSEG[seg]];
#pragma unroll
        for (int k4 = 0; k4 < 4; ++k4) {
            const int ko = k4 * 64;
            __syncthreads();               // previous tile fully consumed
#pragma unroll
            for (int i = 0; i < 4; ++i) {  // 4 issues x 4 waves x 1KB = 16KB per tile
                GL2LDS(As + (size_t)(arow + i * 32 + srow) * 256 + ko + scol,
                       &At[(i * 32 + w * 8) * 64]);
                GL2LDS(Bs + (size_t)(brow + i * 32 + srow) * 256 + ko + scol,
                       &Bt[(i * 32 + w * 8) * 64]);
            }
            __syncthreads();               // drains vmcnt: tiles ready
#pragma unroll
            for (int kk = 0; kk < 2; ++kk) {
                const int co = kk ? coff1 : coff0;
                bf16x8 a[4], b[4];
#pragma unroll
                for (int m = 0; m < 4; ++m)
                    a[m] = *reinterpret_cast<const bf16x8*>(Arow + m * 16 * 64 + co);
#pragma unroll
                for (int n = 0; n < 4; ++n)
                    b[n] = *reinterpret_cast<const bf16x8*>(Brow + n * 16 * 64 + co);
#pragma unroll
                for (int m = 0; m < 4; ++m)
#pragma unroll
                    for (int n = 0; n < 4; ++n)
                        acc[m][n] = __builtin_amdgcn_mfma_f32_16x16x32_bf16(
                            a[m], b[n], acc[m][n], 0, 0, 0);
            }
        }
    }

    // epilogue: fused argmin
    int coln[4]; float cnv[4];
#pragma unroll
    for (int n = 0; n < 4; ++n) {
        coln[n] = brow + wc * 64 + n * 16 + (l & 15);
        cnv[n] = cnorm[coln[n]];
    }
#pragma unroll
    for (int m = 0; m < 4; ++m) {
#pragma unroll
        for (int j = 0; j < 4; ++j) {
            unsigned long long best = 0xFFFFFFFFFFFFFFFFull;
#pragma unroll
            for (int n = 0; n < 4; ++n) {
                float d = fmaf(-2.0f, acc[m][n][j], cnv[n]);
                unsigned u = __float_as_uint(d);
                u = (u & 0x80000000u) ? ~u : (u | 0x80000000u);   // order-preserving map
                unsigned long long pk = ((unsigned long long)u << 32) | (unsigned)coln[n];
                best = pk < best ? pk : best;
            }
#pragma unroll
            for (int mask = 1; mask <= 8; mask <<= 1) {
                unsigned long long o = __shfl_xor(best, mask, 64);
                best = o < best ? o : best;
            }
            if ((l & 15) == 0) {
                const int row = arow + wr * 64 + m * 16 + (l >> 4) * 4 + j;
                atomicMin(&packed[row], best);
            }
        }
    }
}

// ---------------------------------------------------------------------------
// gather (packed): z_q write, out_idx write, vq_loss accumulate
// ---------------------------------------------------------------------------
__global__ __launch_bounds__(256, 2)
void vq_gather_packed_kernel(const float* __restrict__ cb, const float* __restrict__ z,
                             const unsigned long long* __restrict__ packed,
                             float* __restrict__ out_zq, float* __restrict__ out_idx,
                             float* __restrict__ loss)
{
    __shared__ float rows[64 * 257];
    __shared__ int   ks[64];
    __shared__ float wsum[4];

    const int t   = threadIdx.x;
    const int blk = blockIdx.x;            // 512 blocks
    const int b   = blk >> 4;
    const int hw0 = (blk & 15) << 6;
    const int n0  = blk << 6;

    if (t < 64) {
        const int k = (int)(packed[n0 + t] & 0xFFFFFFFFull);
        ks[t] = k;
        out_idx[n0 + t] = (float)k;
    }
    __syncthreads();

#pragma unroll 4
    for (int i = 0; i < 64; ++i) {
        rows[i * 257 + t] = cb[(size_t)ks[i] * 256 + t];
    }
    __syncthreads();

    const int dq = t >> 6;
    const int hw = t & 63;
    const size_t obase = ((size_t)b << 18) + hw0 + hw;
    float sum = 0.f;
#pragma unroll 4
    for (int dd = 0; dd < 64; ++dd) {
        const int d = (dq << 6) + dd;
        const float  q  = rows[hw * 257 + d];
        const size_t a  = obase + (size_t)d * 1024;
        const float  zv = z[a];
        out_zq[a] = q;
        const float diff = q - zv;
        sum = fmaf(diff, diff, sum);
    }
#pragma unroll
    for (int m = 1; m <= 32; m <<= 1) sum += __shfl_xor(sum, m, 64);
    if ((t & 63) == 0) wsum[t >> 6] = sum;
    __syncthreads();
    if (t == 0) {
        const float s = (wsum[0] + wsum[1]) + (wsum[2] + wsum[3]);
        atomicAdd(loss, s * (1.25f / 8388608.0f));   // (1+0.25)*SSE/(B*D*H*W)
    }
}

// ===========================================================================
// FALLBACK PATH (ws too small): round-3 fp32 VALU kernels, known-passing.
// ===========================================================================
__global__ __launch_bounds__(256)
void vq_transpose_kernel(const float* __restrict__ cb, float* __restrict__ ctT)
{
    __shared__ float tile[64 * 65];
    const int t  = threadIdx.x;
    const int kb = blockIdx.x >> 2, db = blockIdx.x & 3;
    const int k0 = kb << 6, d0 = db << 6;
#pragma unroll
    for (int i = 0; i < 16; ++i) {
        int idx = i * 256 + t;
        int r = idx >> 6, c = idx & 63;
        tile[r * 65 + c] = cb[(size_t)(k0 + r) * 256 + d0 + c];
    }
    __syncthreads();
#pragma unroll
    for (int i = 0; i < 16; ++i) {
        int idx = i * 256 + t;
        int r = idx >> 6, c = idx & 63;
        ctT[(size_t)(d0 + r) * 1024 + k0 + c] = tile[c * 65 + r];
    }
}

__global__ __launch_bounds__(512, 2)
void vq_argmin_kernel(const float* __restrict__ z, const float* __restrict__ ctT,
                      const float* __restrict__ cnorm, int* __restrict__ codes,
                      float* __restrict__ out_idx)
{
    __shared__ float zt[256 * 64];
    __shared__ float ct[16 * 256];
    const int t = threadIdx.x, tx = t & 63, ty = t >> 6, p0 = ty << 3;
    const int blk = blockIdx.x, b = blk >> 4, hw0 = (blk & 15) << 6;
    const float* zbase = z + ((size_t)b << 18) + hw0;
#pragma unroll
    for (int i = 0; i < 8; ++i) {
        int idx = i * 512 + t;
        int d = idx >> 4, c4 = (idx & 15) << 2;
        float4 v = *reinterpret_cast<const float4*>(zbase + (size_t)d * 1024 + c4);
        *reinterpret_cast<float4*>(&zt[d * 64 + c4]) = v;
    }
    float minv[8]; int mini[8];
#pragma unroll
    for (int i = 0; i < 8; ++i) { minv[i] = 3.0e38f; mini[i] = 0; }
    const float* zrd = &zt[p0];
    const float* crd = &ct[tx << 2];
    for (int kt = 0; kt < 4; ++kt) {
        const int k0 = kt << 8;
        float acc[8][4];
#pragma unroll
        for (int i = 0; i < 8; ++i)
#pragma unroll
            for (int j = 0; j < 4; ++j) acc[i][j] = 0.f;
        for (int dc = 0; dc < 16; ++dc) {
            const int d0 = dc << 4;
            __syncthreads();
#pragma unroll
            for (int i = 0; i < 2; ++i) {
                int idx = i * 512 + t;
                int r = idx >> 6, c4 = (idx & 63) << 2;
                float4 v = *reinterpret_cast<const float4*>(ctT + (size_t)(d0 + r) * 1024 + k0 + c4);
                *reinterpret_cast<float4*>(&ct[r * 256 + c4]) = v;
            }
            __syncthreads();
            const float* zp = zrd + d0 * 64;
#pragma unroll
            for (int d = 0; d < 16; ++d) {
                float4 za = *reinterpret_cast<const float4*>(zp + d * 64);
                float4 zb = *reinterpret_cast<const float4*>(zp + d * 64 + 4);
                float4 cc = *reinterpret_cast<const float4*>(crd + d * 256);
#define VQ_FMA_ROW(ii, zv)                          \
                acc[ii][0] = fmaf(zv, cc.x, acc[ii][0]); \
                acc[ii][1] = fmaf(zv, cc.y, acc[ii][1]); \
                acc[ii][2] = fmaf(zv, cc.z, acc[ii][2]); \
                acc[ii][3] = fmaf(zv, cc.w, acc[ii][3]);
                VQ_FMA_ROW(0, za.x) VQ_FMA_ROW(1, za.y) VQ_FMA_ROW(2, za.z) VQ_FMA_ROW(3, za.w)
                VQ_FMA_ROW(4, zb.x) VQ_FMA_ROW(5, zb.y) VQ_FMA_ROW(6, zb.z) VQ_FMA_ROW(7, zb.w)
#undef VQ_FMA_ROW
            }
        }
#pragma unroll
        for (int j = 0; j < 4; ++j) {
            const int k = k0 + (tx << 2) + j;
            const float cn = cnorm[k];
#pragma unroll
            for (int i = 0; i < 8; ++i) {
                float dist = fmaf(-2.0f, acc[i][j], cn);
                if (dist < minv[i]) { minv[i] = dist; mini[i] = k; }
            }
        }
    }
#pragma unroll
    for (int m = 1; m <= 32; m <<= 1) {
#pragma unroll
        for (int i = 0; i < 8; ++i) {
            float ov = __shfl_xor(minv[i], m, 64);
            int   oi = __shfl_xor(mini[i], m, 64);
            if (ov < minv[i] || (ov == minv[i] && oi < mini[i])) { minv[i] = ov; mini[i] = oi; }
        }
    }
    if (tx == 0) {
        const int n0 = (blk << 6) + p0;
#pragma unroll
        for (int i = 0; i < 8; ++i) {
            codes[n0 + i]   = mini[i];
            out_idx[n0 + i] = (float)mini[i];
        }
    }
}

__global__ __launch_bounds__(256, 2)
void vq_gather_kernel(const float* __restrict__ cb, const float* __restrict__ z,
                      const int* __restrict__ codes, float* __restrict__ out_zq,
                      float* __restrict__ loss)
{
    __shared__ float rows[64 * 257];
    __shared__ int   ks[64];
    __shared__ float wsum[4];
    const int t = threadIdx.x, blk = blockIdx.x;
    const int b = blk >> 4, hw0 = (blk & 15) << 6, n0 = blk << 6;
    if (t < 64) ks[t] = codes[n0 + t];
    __syncthreads();
#pragma unroll 4
    for (int i = 0; i < 64; ++i) rows[i * 257 + t] = cb[(size_t)ks[i] * 256 + t];
    __syncthreads();
    const int dq = t >> 6, hw = t & 63;
    const size_t obase = ((size_t)b << 18) + hw0 + hw;
    float sum = 0.f;
#pragma unroll 4
    for (int dd = 0; dd < 64; ++dd) {
        const int d = (dq << 6) + dd;
        const float  q  = rows[hw * 257 + d];
        const size_t a  = obase + (size_t)d * 1024;
        const float  zv = z[a];
        out_zq[a] = q;
        const float diff = q - zv;
        sum = fmaf(diff, diff, sum);
    }
#pragma unroll
    for (int m = 1; m <= 32; m <<= 1) sum += __shfl_xor(sum, m, 64);
    if ((t & 63) == 0) wsum[t >> 6] = sum;
    __syncthreads();
    if (t == 0) {
        const float s = (wsum[0] + wsum[1]) + (wsum[2] + wsum[3]);
        atomicAdd(loss, s * (1.25f / 8388608.0f));
    }
}

// ---------------------------------------------------------------------------
extern "C" void kernel_launch(void* const* d_in, const int* in_sizes, int n_in,
                              void* d_out, int out_size, void* d_ws, size_t ws_size,
                              hipStream_t stream)
{
    (void)in_sizes; (void)n_in; (void)out_size;

    const float* z  = (const float*)d_in[0];   // 32*256*32*32 fp32
    const float* cb = (const float*)d_in[1];   // 1024*256 fp32

    float* out      = (float*)d_out;
    float* out_zq   = out;                     // 8388608
    float* out_idx  = out + 8388608;           // 32768 (indices as float values)
    float* out_loss = out + 8421376;           // 1

    // MFMA-path workspace: packed(256KB) | z0|z1|z2 (16MB each) | c0|c1|c2 | cnorm
    const size_t NEED = 262144ull + 3ull * 16777216ull + 3ull * 524288ull + 4096ull;

    if (ws_size >= NEED) {
        unsigned long long* packed = (unsigned long long*)d_ws;
        unsigned short* z0 = (unsigned short*)((char*)d_ws + 262144);
        unsigned short* z1 = z0 + 8388608u;
        unsigned short* z2 = z1 + 8388608u;
        unsigned short* c0 = z2 + 8388608u;
        unsigned short* c1 = c0 + 262144u;
        unsigned short* c2 = c1 + 262144u;
        float* cnorm = (float*)(c2 + 262144u);

        hipMemsetAsync(out_loss, 0, sizeof(float), stream);
        hipMemsetAsync(packed, 0xFF, 262144, stream);
        vq_csplit_kernel<<<256, 256, 0, stream>>>(cb, c0, c1, c2);
        vq_cnorm_kernel<<<4, 256, 0, stream>>>(cb, cnorm);
        vq_zsplit_kernel<<<512, 256, 0, stream>>>(z, z0, z1, z2);
        vq_mfma_argmin_kernel<<<2048, 256, 0, stream>>>(z0, c0, cnorm, packed);
        vq_gather_packed_kernel<<<512, 256, 0, stream>>>(cb, z, packed, out_zq, out_idx, out_loss);
    } else {
        // fallback: round-3 fp32 path (ws >= 1.38MB known OK)
        float* ctT   = (float*)d_ws;
        float* cnorm = ctT + 256 * 1024;
        int*   codes = (int*)(cnorm + 1024);

        hipMemsetAsync(out_loss, 0, sizeof(float), stream);
        vq_transpose_kernel<<<64, 256, 0, stream>>>(cb, ctT);
        vq_cnorm_kernel<<<4, 256, 0, stream>>>(cb, cnorm);
        vq_argmin_kernel<<<512, 512, 0, stream>>>(z, ctT, cnorm, codes, out_idx);
        vq_gather_kernel<<<512, 256, 0, stream>>>(cb, z, codes, out_zq, out_loss);
    }
}